// Round 17
// baseline (211.185 us; speedup 1.0000x reference)
//
#include <hip/hip_runtime.h>
#include <hip/hip_bf16.h>

#define BATCH 4096
#define NEXP  16
#define DIN   2048
#define DOUT  2048

#define BM 128
#define BN 32
#define NKT 64            // 64 k-tiles of 32 elements; processed as 32 pairs
#define NPAIR 32

#define WS_X_OFF   65536
#define PADROWS    4352   // 4096 + 16*16 worst-case padding
#define WS_X_BYTES ((size_t)PADROWS * 4096)

typedef __attribute__((ext_vector_type(4))) float f32x4;
typedef __attribute__((ext_vector_type(8))) short bf16x8;

// --- Kernel 1: bucket sample indices by expert; write mxs/actions tail ---
// poffs[e]: 16-aligned padded offsets (fragment groups never cross experts).
__global__ void sort_kernel(const int* __restrict__ actions,
                            const float* __restrict__ mxs,
                            float* __restrict__ out_tail,
                            int* __restrict__ offs,     // [17]
                            int* __restrict__ poffs,    // [17]
                            int* __restrict__ sorted) {
    __shared__ int s_cnt[NEXP];
    __shared__ int s_cur[NEXP];
    const int tid = threadIdx.x;
    if (tid < NEXP) s_cnt[tid] = 0;
    __syncthreads();
    for (int i = tid; i < BATCH; i += blockDim.x) {
        int a = actions[i];
        atomicAdd(&s_cnt[a], 1);
        out_tail[i] = mxs[i];
        out_tail[BATCH + i] = (float)a;
    }
    __syncthreads();
    if (tid == 0) {
        int run = 0, prun = 0;
        for (int e = 0; e < NEXP; ++e) {
            offs[e] = run;  s_cur[e] = run;
            poffs[e] = prun;
            run += s_cnt[e];
            prun += (s_cnt[e] + 15) & ~15;
        }
        offs[NEXP] = run;
        poffs[NEXP] = prun;
    }
    __syncthreads();
    // Bucket order is atomics-dependent, but each sample's output is computed
    // independently with fixed k-order -> output bit-deterministic.
    for (int i = tid; i < BATCH; i += blockDim.x) {
        int e = actions[i];
        int pos = atomicAdd(&s_cur[e], 1);
        sorted[pos] = i;
    }
}

// fp32 pair -> packed bf16 (round-to-nearest-even): [bf16(x1) | bf16(x0)]
__device__ __forceinline__ unsigned rne2(float x0, float x1) {
    unsigned b0 = __float_as_uint(x0), b1 = __float_as_uint(x1);
    b0 = b0 + 0x7FFFu + ((b0 >> 16) & 1u);
    b1 = b1 + 0x7FFFu + ((b1 >> 16) & 1u);
    return (b1 & 0xFFFF0000u) | (b0 >> 16);
}

// W LDS tile [R][64 bf16] (one kt-PAIR): row = 128 B = 8 x 16B blocks,
// physical block = kb ^ (r&7). Write (8 threads/row over 8 blocks) and
// read (16-lane group, kb fixed, rows 0..15) are both 2-way -> free
// (measured ~0 conflicts r12/r15 with the same function).
__device__ __forceinline__ int lidxW(int r, int kb) {
    return r * 64 + ((kb ^ (r & 7)) << 3);
}

// --- Kernel 1b: X -> bf16 fragments, A-fragment-major ---
// Group = 16 padded rows of one expert = 64 KB: addr = grp*65536 + kt*1024
// + g*256 + slot*16. GEMM lane l reads grpbase + kt*1024 + l*16.
__global__ void xsplit_kernel(const float* __restrict__ xs,
                              const int* __restrict__ sorted,
                              const int* __restrict__ offs,
                              const int* __restrict__ poffs,
                              unsigned char* __restrict__ xws) {
    const int t = threadIdx.x;
    const int slot = t & 15;
    const int ktq = t >> 4;                 // 0..15, covers kt = ktq*4..+3
    const int p = blockIdx.x * 16 + slot;   // padded row index
    if (p >= poffs[NEXP]) return;
    int e = 0;
#pragma unroll
    for (int i = 1; i < NEXP; ++i)
        if (p >= poffs[i]) e = i;
    const int local = p - poffs[e];
    if (local >= offs[e + 1] - offs[e]) return;   // tail pad row
    const int src = sorted[offs[e] + local];
    const float* srow = xs + (size_t)src * DIN;
    unsigned char* gbase = xws + (size_t)blockIdx.x * 65536;
#pragma unroll
    for (int q = 0; q < 4; ++q) {
        const int kt = ktq * 4 + q;
        const float* s = srow + kt * 32;
        uint4 L[4];
#pragma unroll
        for (int j = 0; j < 4; ++j) {
            float4 a = *(const float4*)(s + 8 * j);
            float4 b = *(const float4*)(s + 8 * j + 4);
            L[j].x = rne2(a.x, a.y); L[j].y = rne2(a.z, a.w);
            L[j].z = rne2(b.x, b.y); L[j].w = rne2(b.z, b.w);
        }
        unsigned char* d = gbase + kt * 1024 + slot * 16;
#pragma unroll
        for (int g = 0; g < 4; ++g)
            *(uint4*)(d + g * 256) = L[g];
    }
}

// --- Kernel 2: grouped GEMM, pure bf16. r15's exact KSTEP schedule with
// BN=32: 2048 active blocks (5-8/CU, ~20 waves/CU) — single-variable TLP
// test. W tile [32][64] per pair, 1 float4x2 load + 1 conv + 1 ds_write
// per thread per period. X A-frags direct from xws. Waves 4x1 (32r x 32c).
// grid = (n=64 fastest, e=16, m=32); block 256.
__global__ __launch_bounds__(256, 4)
void gemm_kernel(const unsigned char* __restrict__ xws,
                 const float* __restrict__ W,
                 const float* __restrict__ bias,
                 const int* __restrict__ offs,
                 const int* __restrict__ poffs,
                 const int* __restrict__ sorted,
                 float* __restrict__ out) {
    __shared__ __align__(16) unsigned short Wl[2][BN * 64];  // 2 x 4 KB

    const int e = blockIdx.y;
    const int start = offs[e];
    const int cnt = offs[e + 1] - start;
    const int m0 = blockIdx.z * BM;
    if (m0 >= cnt) return;
    const int n0 = blockIdx.x * BN;

    const int tid = threadIdx.x;
    const int lane = tid & 63;
    const int wave = tid >> 6;
    const int g = lane >> 4, rl = lane & 15;

    // W staging: row swr (0..31), 8-fp32 chunk wkq (0..7) per pair.
    const int swr = tid >> 3;
    const int wkq = tid & 7;
    const float* wsrc = W + ((size_t)e * DOUT + n0 + swr) * DIN + wkq * 8;

    // X fragment group bases; clamp keeps OOB staging in-bounds (clamped
    // groups only hold rows >= cnt, masked at the epilogue).
    const unsigned char* xb[2];
#pragma unroll
    for (int mi = 0; mi < 2; ++mi) {
        int prow = poffs[e] + m0 + wave * 32 + mi * 16;
        if (prow > PADROWS - 16) prow = PADROWS - 16;
        xb[mi] = xws + ((size_t)prow >> 4) * 65536 + (size_t)lane * 16;
    }

    f32x4 acc[2][2];
#pragma unroll
    for (int i = 0; i < 2; ++i)
#pragma unroll
        for (int j = 0; j < 2; ++j) acc[i][j] = (f32x4){0.f, 0.f, 0.f, 0.f};

    // ---- prologue ----
    float4 pwA[2], pwB[2];
    pwA[0] = *(const float4*)(wsrc);             // pair 0
    pwA[1] = *(const float4*)(wsrc + 4);
    pwB[0] = *(const float4*)(wsrc + 64);        // pair 1
    pwB[1] = *(const float4*)(wsrc + 64 + 4);
    bf16x8 axA[2][2], axB[2][2];
#pragma unroll
    for (int mi = 0; mi < 2; ++mi) {
        axA[mi][0] = *(const bf16x8*)(xb[mi]);            // kt 0
        axA[mi][1] = *(const bf16x8*)(xb[mi] + 1024);     // kt 1
    }
    {   // pre-loop: conv + ds_write pair 0 into buf 0; reload pwA with pair 2
        uint4 u;
        u.x = rne2(pwA[0].x, pwA[0].y); u.y = rne2(pwA[0].z, pwA[0].w);
        u.z = rne2(pwA[1].x, pwA[1].y); u.w = rne2(pwA[1].z, pwA[1].w);
        *(uint4*)&Wl[0][lidxW(swr, wkq)] = u;
        pwA[0] = *(const float4*)(wsrc + 128);
        pwA[1] = *(const float4*)(wsrc + 128 + 4);
    }

    int pr = 0;   // pair index

    // Per KSTEP(pair pr): [lgkm0 + barrier] -> read W frags (buf pr&1) ->
    // issue X(pair pr+1) -> conv+write W(pair pr+1) into other buf ->
    // reload PWU with W(pair pr+3) -> 8 MFMA.
    // Race audit (r15): reads of buf B in KSTEP p drain (own lgkmcnt(0))
    // before the barrier of KSTEP p+1, which precedes writes to buf B.
#define KSTEP(AXC, AXN, PWU, PAR) do {                                         \
    __builtin_amdgcn_sched_barrier(0);                                         \
    asm volatile("s_waitcnt lgkmcnt(0)");                                      \
    __builtin_amdgcn_sched_barrier(0);                                         \
    __builtin_amdgcn_s_barrier();                                              \
    __builtin_amdgcn_sched_barrier(0);                                         \
    bf16x8 bh[2][2];                                                           \
    _Pragma("unroll")                                                          \
    for (int j = 0; j < 2; ++j)                                                \
        _Pragma("unroll")                                                      \
        for (int ni = 0; ni < 2; ++ni)                                         \
            bh[j][ni] = *(const bf16x8*)&Wl[PAR][lidxW(ni * 16 + rl, j * 4 + g)]; \
    { /* X(pair pr+1) loads -> AXN (wrap: harmless reload) */                  \
      int _kn = ((pr + 1) & (NPAIR - 1)) * 2;                                  \
      _Pragma("unroll")                                                        \
      for (int mi = 0; mi < 2; ++mi) {                                         \
          AXN[mi][0] = *(const bf16x8*)(xb[mi] + (size_t)_kn * 1024);          \
          AXN[mi][1] = *(const bf16x8*)(xb[mi] + (size_t)(_kn + 1) * 1024);    \
      } }                                                                      \
    { /* conv + ds_write W(pair pr+1) into other buffer */                     \
      uint4 u;                                                                 \
      u.x = rne2(PWU[0].x, PWU[0].y); u.y = rne2(PWU[0].z, PWU[0].w);          \
      u.z = rne2(PWU[1].x, PWU[1].y); u.w = rne2(PWU[1].z, PWU[1].w);          \
      *(uint4*)&Wl[PAR ^ 1][lidxW(swr, wkq)] = u; }                            \
    { /* reload PWU with W(pair pr+3) */                                       \
      int _k3 = (pr + 3) & (NPAIR - 1);                                        \
      PWU[0] = *(const float4*)(wsrc + (size_t)_k3 * 64);                      \
      PWU[1] = *(const float4*)(wsrc + (size_t)_k3 * 64 + 4); }                \
    __builtin_amdgcn_s_setprio(1);                                             \
    _Pragma("unroll")                                                          \
    for (int j = 0; j < 2; ++j)                                                \
        _Pragma("unroll")                                                      \
        for (int mi = 0; mi < 2; ++mi)                                         \
            _Pragma("unroll")                                                  \
            for (int ni = 0; ni < 2; ++ni)                                     \
                acc[mi][ni] = __builtin_amdgcn_mfma_f32_16x16x32_bf16(AXC[mi][j], bh[j][ni], acc[mi][ni], 0, 0, 0); \
    __builtin_amdgcn_s_setprio(0);                                             \
    ++pr;                                                                      \
} while (0)

#pragma unroll 1
    for (int it = 0; it < NPAIR / 2; ++it) {
        KSTEP(axA, axB, pwB, 0);   // even pair: X in axA, W buf 0
        KSTEP(axB, axA, pwA, 1);   // odd  pair
    }
#undef KSTEP

    // ---- epilogue: bias add + scatter rows (4x1 wave layout) ----
    float bv[2];
#pragma unroll
    for (int ni = 0; ni < 2; ++ni)
        bv[ni] = bias[(size_t)e * DOUT + n0 + ni * 16 + rl];
#pragma unroll
    for (int mi = 0; mi < 2; ++mi) {
#pragma unroll
        for (int j = 0; j < 4; ++j) {
            int rm = m0 + wave * 32 + mi * 16 + g * 4 + j;
            if (rm < cnt) {
                int s = sorted[start + rm];
                float* orow = out + (size_t)s * DOUT + n0 + rl;
#pragma unroll
                for (int ni = 0; ni < 2; ++ni)
                    orow[ni * 16] = acc[mi][ni][j] + bv[ni];
            }
        }
    }
}

// --- Fallback: r15 kernel (proven 163.9 us total) if ws too small ---
__global__ __launch_bounds__(256, 3)
void gemm_lds(const unsigned char* __restrict__ xws,
              const float* __restrict__ W,
              const float* __restrict__ bias,
              const int* __restrict__ offs,
              const int* __restrict__ poffs,
              const int* __restrict__ sorted,
              float* __restrict__ out) {
    __shared__ __align__(16) unsigned short Wl[2][64 * 64];

    const int e = blockIdx.y;
    const int start = offs[e];
    const int cnt = offs[e + 1] - start;
    const int m0 = blockIdx.z * BM;
    if (m0 >= cnt) return;
    const int n0 = blockIdx.x * 64;

    const int tid = threadIdx.x;
    const int lane = tid & 63;
    const int wave = tid >> 6;
    const int g = lane >> 4, rl = lane & 15;

    const int swr = tid >> 2;
    const int wkq = tid & 3;
    const float* wsrc = W + ((size_t)e * DOUT + n0 + swr) * DIN + wkq * 16;

    const unsigned char* xb[2];
#pragma unroll
    for (int mi = 0; mi < 2; ++mi) {
        int prow = poffs[e] + m0 + wave * 32 + mi * 16;
        if (prow > PADROWS - 16) prow = PADROWS - 16;
        xb[mi] = xws + ((size_t)prow >> 4) * 65536 + (size_t)lane * 16;
    }

    f32x4 acc[2][4];
#pragma unroll
    for (int i = 0; i < 2; ++i)
#pragma unroll
        for (int j = 0; j < 4; ++j) acc[i][j] = (f32x4){0.f, 0.f, 0.f, 0.f};

    float4 pwA[4], pwB[4];
#pragma unroll
    for (int j = 0; j < 4; ++j) pwA[j] = *(const float4*)(wsrc + 0 * 64 + 4 * j);
#pragma unroll
    for (int j = 0; j < 4; ++j) pwB[j] = *(const float4*)(wsrc + 1 * 64 + 4 * j);
    bf16x8 axA[2][2], axB[2][2];
#pragma unroll
    for (int mi = 0; mi < 2; ++mi) {
        axA[mi][0] = *(const bf16x8*)(xb[mi]);
        axA[mi][1] = *(const bf16x8*)(xb[mi] + 1024);
    }
    {
        uint4 u0, u1;
        u0.x = rne2(pwA[0].x, pwA[0].y); u0.y = rne2(pwA[0].z, pwA[0].w);
        u0.z = rne2(pwA[1].x, pwA[1].y); u0.w = rne2(pwA[1].z, pwA[1].w);
        u1.x = rne2(pwA[2].x, pwA[2].y); u1.y = rne2(pwA[2].z, pwA[2].w);
        u1.z = rne2(pwA[3].x, pwA[3].y); u1.w = rne2(pwA[3].z, pwA[3].w);
        *(uint4*)&Wl[0][lidxW(swr, 2 * wkq)]     = u0;
        *(uint4*)&Wl[0][lidxW(swr, 2 * wkq + 1)] = u1;
#pragma unroll
        for (int j = 0; j < 4; ++j) pwA[j] = *(const float4*)(wsrc + 2 * 64 + 4 * j);
    }

    int pr = 0;

#define KSTEP(AXC, AXN, PWU, PAR) do {                                         \
    __builtin_amdgcn_sched_barrier(0);                                         \
    asm volatile("s_waitcnt lgkmcnt(0)");                                      \
    __builtin_amdgcn_sched_barrier(0);                                         \
    __builtin_amdgcn_s_barrier();                                              \
    __builtin_amdgcn_sched_barrier(0);                                         \
    bf16x8 bh[2][4];                                                           \
    _Pragma("unroll")                                                          \
    for (int j = 0; j < 2; ++j)                                                \
        _Pragma("unroll")                                                      \
        for (int ni = 0; ni < 4; ++ni)                                         \
            bh[j][ni] = *(const bf16x8*)&Wl[PAR][lidxW(ni * 16 + rl, j * 4 + g)]; \
    { int _kn = ((pr + 1) & (NPAIR - 1)) * 2;                                  \
      _Pragma("unroll")                                                        \
      for (int mi = 0; mi < 2; ++mi) {                                         \
          AXN[mi][0] = *(const bf16x8*)(xb[mi] + (size_t)_kn * 1024);          \
          AXN[mi][1] = *(const bf16x8*)(xb[mi] + (size_t)(_kn + 1) * 1024);    \
      } }                                                                      \
    { uint4 u0, u1;                                                            \
      u0.x = rne2(PWU[0].x, PWU[0].y); u0.y = rne2(PWU[0].z, PWU[0].w);        \
      u0.z = rne2(PWU[1].x, PWU[1].y); u0.w = rne2(PWU[1].z, PWU[1].w);        \
      u1.x = rne2(PWU[2].x, PWU[2].y); u1.y = rne2(PWU[2].z, PWU[2].w);        \
      u1.z = rne2(PWU[3].x, PWU[3].y); u1.w = rne2(PWU[3].z, PWU[3].w);        \
      *(uint4*)&Wl[PAR ^ 1][lidxW(swr, 2 * wkq)]     = u0;                     \
      *(uint4*)&Wl[PAR ^ 1][lidxW(swr, 2 * wkq + 1)] = u1; }                   \
    { int _k3 = (pr + 3) & (NPAIR - 1);                                        \
      _Pragma("unroll")                                                        \
      for (int j = 0; j < 4; ++j)                                              \
          PWU[j] = *(const float4*)(wsrc + (size_t)_k3 * 64 + 4 * j); }        \
    __builtin_amdgcn_s_setprio(1);                                             \
    _Pragma("unroll")                                                          \
    for (int j = 0; j < 2; ++j)                                                \
        _Pragma("unroll")                                                      \
        for (int mi = 0; mi < 2; ++mi)                                         \
            _Pragma("unroll")                                                  \
            for (int ni = 0; ni < 4; ++ni)                                     \
                acc[mi][ni] = __builtin_amdgcn_mfma_f32_16x16x32_bf16(AXC[mi][j], bh[j][ni], acc[mi][ni], 0, 0, 0); \
    __builtin_amdgcn_s_setprio(0);                                             \
    ++pr;                                                                      \
} while (0)

#pragma unroll 1
    for (int it = 0; it < NPAIR / 2; ++it) {
        KSTEP(axA, axB, pwB, 0);
        KSTEP(axB, axA, pwA, 1);
    }
#undef KSTEP

    float bv[4];
#pragma unroll
    for (int ni = 0; ni < 4; ++ni)
        bv[ni] = bias[(size_t)e * DOUT + n0 + ni * 16 + rl];
#pragma unroll
    for (int mi = 0; mi < 2; ++mi) {
#pragma unroll
        for (int j = 0; j < 4; ++j) {
            int rm = m0 + wave * 32 + mi * 16 + g * 4 + j;
            if (rm < cnt) {
                int s = sorted[start + rm];
                float* orow = out + (size_t)s * DOUT + n0 + rl;
#pragma unroll
                for (int ni = 0; ni < 4; ++ni)
                    orow[ni * 16] = acc[mi][ni][j] + bv[ni];
            }
        }
    }
}

extern "C" void kernel_launch(void* const* d_in, const int* in_sizes, int n_in,
                              void* d_out, int out_size, void* d_ws, size_t ws_size,
                              hipStream_t stream) {
    const float* xs      = (const float*)d_in[0];
    const float* mxs     = (const float*)d_in[1];
    const int*   actions = (const int*)d_in[2];
    const float* W       = (const float*)d_in[3];
    const float* b       = (const float*)d_in[4];
    float* out = (float*)d_out;

    int* ws_i   = (int*)d_ws;
    int* offs   = ws_i;          // [17]
    int* poffs  = ws_i + 20;     // [17]
    int* sorted = ws_i + 64;     // [BATCH]

    sort_kernel<<<1, 1024, 0, stream>>>(actions, mxs,
                                        out + (size_t)BATCH * DOUT,
                                        offs, poffs, sorted);

    unsigned char* xws = (unsigned char*)d_ws + WS_X_OFF;
    xsplit_kernel<<<PADROWS / 16, 256, 0, stream>>>(xs, sorted, offs, poffs, xws);

    if (ws_size >= WS_X_OFF + WS_X_BYTES) {
        dim3 grid(DOUT / BN, NEXP, BATCH / BM);   // (64, 16, 32), n fastest
        gemm_kernel<<<grid, 256, 0, stream>>>(xws, W, b, offs, poffs, sorted, out);
    } else {
        dim3 grid(DOUT / 64, NEXP, BATCH / BM);
        gemm_lds<<<grid, 256, 0, stream>>>(xws, W, b, offs, poffs, sorted, out);
    }
}

// Round 18
// 178.111 us; speedup vs baseline: 1.1857x; 1.1857x over previous
//
#include <hip/hip_runtime.h>
#include <hip/hip_bf16.h>

#define BATCH 4096
#define NEXP  16
#define DIN   2048
#define DOUT  2048

#define BM 128
#define BN 64
#define NKT 64            // 64 k-tiles of 32 elements; processed as 32 pairs
#define NPAIR 32
#define NMT_MAX 48        // sum ceil(cnt_e/BM) <= 47

#define WS_X_OFF   65536
#define PADROWS    4352   // 4096 + 16*16 worst-case padding
#define WS_X_BYTES ((size_t)PADROWS * 4096)

typedef __attribute__((ext_vector_type(4))) float f32x4;
typedef __attribute__((ext_vector_type(8))) short bf16x8;

// --- Kernel 1: bucket sample indices by expert; write mxs/actions tail ---
// Also: poffs[e] (16-aligned padded offsets) and the compacted m-tile table
// (mte[mt], mtm0[mt]) so the GEMM grid has the ~2 m-tiles of each (e, n)
// ADJACENT in dispatch order -> W panel's 2nd read hits L2/L3, not HBM.
__global__ void sort_kernel(const int* __restrict__ actions,
                            const float* __restrict__ mxs,
                            float* __restrict__ out_tail,
                            int* __restrict__ offs,     // [17]
                            int* __restrict__ poffs,    // [17]
                            int* __restrict__ sorted,   // [BATCH]
                            int* __restrict__ mte,      // [NMT_MAX]
                            int* __restrict__ mtm0) {   // [NMT_MAX]
    __shared__ int s_cnt[NEXP];
    __shared__ int s_cur[NEXP];
    const int tid = threadIdx.x;
    if (tid < NEXP) s_cnt[tid] = 0;
    __syncthreads();
    for (int i = tid; i < BATCH; i += blockDim.x) {
        int a = actions[i];
        atomicAdd(&s_cnt[a], 1);
        out_tail[i] = mxs[i];
        out_tail[BATCH + i] = (float)a;
    }
    __syncthreads();
    if (tid == 0) {
        int run = 0, prun = 0, nmt = 0;
        for (int e = 0; e < NEXP; ++e) {
            offs[e] = run;  s_cur[e] = run;
            poffs[e] = prun;
            for (int m0 = 0; m0 < s_cnt[e]; m0 += BM) {
                mte[nmt] = e; mtm0[nmt] = m0; ++nmt;
            }
            run += s_cnt[e];
            prun += (s_cnt[e] + 15) & ~15;
        }
        offs[NEXP] = run;
        poffs[NEXP] = prun;
        for (; nmt < NMT_MAX; ++nmt) { mte[nmt] = -1; mtm0[nmt] = 0; }
    }
    __syncthreads();
    // Bucket order is atomics-dependent, but each sample's output is computed
    // independently with fixed k-order -> output bit-deterministic.
    for (int i = tid; i < BATCH; i += blockDim.x) {
        int e = actions[i];
        int pos = atomicAdd(&s_cur[e], 1);
        sorted[pos] = i;
    }
}

// fp32 pair -> packed bf16 (round-to-nearest-even): [bf16(x1) | bf16(x0)]
__device__ __forceinline__ unsigned rne2(float x0, float x1) {
    unsigned b0 = __float_as_uint(x0), b1 = __float_as_uint(x1);
    b0 = b0 + 0x7FFFu + ((b0 >> 16) & 1u);
    b1 = b1 + 0x7FFFu + ((b1 >> 16) & 1u);
    return (b1 & 0xFFFF0000u) | (b0 >> 16);
}

// W LDS tile [64 rows][64 bf16] (one kt-PAIR): row = 128 B = 8 x 16B blocks,
// physical block = kb ^ (r&7). Write and read both 2-way -> free
// (measured ~0 conflicts r12/r15/r17 with the same function).
__device__ __forceinline__ int lidxW(int r, int kb) {
    return r * 64 + ((kb ^ (r & 7)) << 3);
}

// --- Kernel 1b: X -> bf16 fragments, A-fragment-major ---
// Group = 16 padded rows of one expert = 64 KB: addr = grp*65536 + kt*1024
// + g*256 + slot*16. GEMM lane l reads grpbase + kt*1024 + l*16.
__global__ void xsplit_kernel(const float* __restrict__ xs,
                              const int* __restrict__ sorted,
                              const int* __restrict__ offs,
                              const int* __restrict__ poffs,
                              unsigned char* __restrict__ xws) {
    const int t = threadIdx.x;
    const int slot = t & 15;
    const int ktq = t >> 4;                 // 0..15, covers kt = ktq*4..+3
    const int p = blockIdx.x * 16 + slot;   // padded row index
    if (p >= poffs[NEXP]) return;
    int e = 0;
#pragma unroll
    for (int i = 1; i < NEXP; ++i)
        if (p >= poffs[i]) e = i;
    const int local = p - poffs[e];
    if (local >= offs[e + 1] - offs[e]) return;   // tail pad row
    const int src = sorted[offs[e] + local];
    const float* srow = xs + (size_t)src * DIN;
    unsigned char* gbase = xws + (size_t)blockIdx.x * 65536;
#pragma unroll
    for (int q = 0; q < 4; ++q) {
        const int kt = ktq * 4 + q;
        const float* s = srow + kt * 32;
        uint4 L[4];
#pragma unroll
        for (int j = 0; j < 4; ++j) {
            float4 a = *(const float4*)(s + 8 * j);
            float4 b = *(const float4*)(s + 8 * j + 4);
            L[j].x = rne2(a.x, a.y); L[j].y = rne2(a.z, a.w);
            L[j].z = rne2(b.x, b.y); L[j].w = rne2(b.z, b.w);
        }
        unsigned char* d = gbase + kt * 1024 + slot * 16;
#pragma unroll
        for (int g = 0; g < 4; ++g)
            *(uint4*)(d + g * 256) = L[g];
    }
}

// --- Kernel 2: grouped GEMM, pure bf16 — r15's exact proven KSTEP schedule
// (best known: 163.6 us total). ONLY change: grid = (mt fastest, n), with
// (e, m0) from the compacted tile table -> W-panel m-pairs adjacent in
// dispatch -> second W read is an L2/L3 hit (FETCH 450->~300 MB predicted).
__global__ __launch_bounds__(256, 3)
void gemm_kernel(const unsigned char* __restrict__ xws,
                 const float* __restrict__ W,
                 const float* __restrict__ bias,
                 const int* __restrict__ offs,
                 const int* __restrict__ poffs,
                 const int* __restrict__ sorted,
                 const int* __restrict__ mte,
                 const int* __restrict__ mtm0,
                 float* __restrict__ out) {
    __shared__ __align__(16) unsigned short Wl[2][BN * 64];  // 2 x 8 KB

    const int e = mte[blockIdx.x];
    if (e < 0) return;
    const int m0 = mtm0[blockIdx.x];
    const int start = offs[e];
    const int cnt = offs[e + 1] - start;
    const int n0 = blockIdx.y * BN;

    const int tid = threadIdx.x;
    const int lane = tid & 63;
    const int wave = tid >> 6;
    const int g = lane >> 4, rl = lane & 15;

    // W staging: row swr (0..63), 16-fp32 chunk wkq (0..3) per pair.
    const int swr = tid >> 2;
    const int wkq = tid & 3;
    const float* wsrc = W + ((size_t)e * DOUT + n0 + swr) * DIN + wkq * 16;

    // X fragment group bases; clamp keeps OOB staging in-bounds (clamped
    // groups only hold rows >= cnt, masked at the epilogue).
    const unsigned char* xb[2];
#pragma unroll
    for (int mi = 0; mi < 2; ++mi) {
        int prow = poffs[e] + m0 + wave * 32 + mi * 16;
        if (prow > PADROWS - 16) prow = PADROWS - 16;
        xb[mi] = xws + ((size_t)prow >> 4) * 65536 + (size_t)lane * 16;
    }

    f32x4 acc[2][4];
#pragma unroll
    for (int i = 0; i < 2; ++i)
#pragma unroll
        for (int j = 0; j < 4; ++j) acc[i][j] = (f32x4){0.f, 0.f, 0.f, 0.f};

    // ---- prologue ----
    float4 pwA[4], pwB[4];
#pragma unroll
    for (int j = 0; j < 4; ++j) pwA[j] = *(const float4*)(wsrc + 0 * 64 + 4 * j);
#pragma unroll
    for (int j = 0; j < 4; ++j) pwB[j] = *(const float4*)(wsrc + 1 * 64 + 4 * j);
    bf16x8 axA[2][2], axB[2][2];
#pragma unroll
    for (int mi = 0; mi < 2; ++mi) {
        axA[mi][0] = *(const bf16x8*)(xb[mi]);
        axA[mi][1] = *(const bf16x8*)(xb[mi] + 1024);
    }
    {   // pre-loop: conv + ds_write pair 0 into buf 0; reload pwA with pair 2
        uint4 u0, u1;
        u0.x = rne2(pwA[0].x, pwA[0].y); u0.y = rne2(pwA[0].z, pwA[0].w);
        u0.z = rne2(pwA[1].x, pwA[1].y); u0.w = rne2(pwA[1].z, pwA[1].w);
        u1.x = rne2(pwA[2].x, pwA[2].y); u1.y = rne2(pwA[2].z, pwA[2].w);
        u1.z = rne2(pwA[3].x, pwA[3].y); u1.w = rne2(pwA[3].z, pwA[3].w);
        *(uint4*)&Wl[0][lidxW(swr, 2 * wkq)]     = u0;
        *(uint4*)&Wl[0][lidxW(swr, 2 * wkq + 1)] = u1;
#pragma unroll
        for (int j = 0; j < 4; ++j) pwA[j] = *(const float4*)(wsrc + 2 * 64 + 4 * j);
    }

    int pr = 0;   // pair index

    // Per KSTEP(pair pr): [lgkm0 + barrier] -> read W frags (buf pr&1) ->
    // issue X(pair pr+1) -> conv+write W(pair pr+1) into other buf ->
    // reload PWU with W(pair pr+3) -> 16 MFMA.
    // Race audit (r15): reads of buf B in KSTEP p drain (own lgkmcnt(0))
    // before the barrier of KSTEP p+1, which precedes writes to buf B.
#define KSTEP(AXC, AXN, PWU, PAR) do {                                         \
    __builtin_amdgcn_sched_barrier(0);                                         \
    asm volatile("s_waitcnt lgkmcnt(0)");                                      \
    __builtin_amdgcn_sched_barrier(0);                                         \
    __builtin_amdgcn_s_barrier();                                              \
    __builtin_amdgcn_sched_barrier(0);                                         \
    bf16x8 bh[2][4];                                                           \
    _Pragma("unroll")                                                          \
    for (int j = 0; j < 2; ++j)                                                \
        _Pragma("unroll")                                                      \
        for (int ni = 0; ni < 4; ++ni)                                         \
            bh[j][ni] = *(const bf16x8*)&Wl[PAR][lidxW(ni * 16 + rl, j * 4 + g)]; \
    { /* X(pair pr+1) loads -> AXN (wrap: harmless reload) */                  \
      int _kn = ((pr + 1) & (NPAIR - 1)) * 2;                                  \
      _Pragma("unroll")                                                        \
      for (int mi = 0; mi < 2; ++mi) {                                         \
          AXN[mi][0] = *(const bf16x8*)(xb[mi] + (size_t)_kn * 1024);          \
          AXN[mi][1] = *(const bf16x8*)(xb[mi] + (size_t)(_kn + 1) * 1024);    \
      } }                                                                      \
    { /* conv + ds_write W(pair pr+1) into other buffer */                     \
      uint4 u0, u1;                                                            \
      u0.x = rne2(PWU[0].x, PWU[0].y); u0.y = rne2(PWU[0].z, PWU[0].w);        \
      u0.z = rne2(PWU[1].x, PWU[1].y); u0.w = rne2(PWU[1].z, PWU[1].w);        \
      u1.x = rne2(PWU[2].x, PWU[2].y); u1.y = rne2(PWU[2].z, PWU[2].w);        \
      u1.z = rne2(PWU[3].x, PWU[3].y); u1.w = rne2(PWU[3].z, PWU[3].w);        \
      *(uint4*)&Wl[PAR ^ 1][lidxW(swr, 2 * wkq)]     = u0;                     \
      *(uint4*)&Wl[PAR ^ 1][lidxW(swr, 2 * wkq + 1)] = u1; }                   \
    { /* reload PWU with W(pair pr+3) */                                       \
      int _k3 = (pr + 3) & (NPAIR - 1);                                        \
      _Pragma("unroll")                                                        \
      for (int j = 0; j < 4; ++j)                                              \
          PWU[j] = *(const float4*)(wsrc + (size_t)_k3 * 64 + 4 * j); }        \
    __builtin_amdgcn_s_setprio(1);                                             \
    _Pragma("unroll")                                                          \
    for (int j = 0; j < 2; ++j)                                                \
        _Pragma("unroll")                                                      \
        for (int mi = 0; mi < 2; ++mi)                                         \
            _Pragma("unroll")                                                  \
            for (int ni = 0; ni < 4; ++ni)                                     \
                acc[mi][ni] = __builtin_amdgcn_mfma_f32_16x16x32_bf16(AXC[mi][j], bh[j][ni], acc[mi][ni], 0, 0, 0); \
    __builtin_amdgcn_s_setprio(0);                                             \
    ++pr;                                                                      \
} while (0)

#pragma unroll 1
    for (int it = 0; it < NPAIR / 2; ++it) {
        KSTEP(axA, axB, pwB, 0);   // even pair: X in axA, W buf 0
        KSTEP(axB, axA, pwA, 1);   // odd  pair
    }
#undef KSTEP

    // ---- epilogue: bias add + scatter rows (4x1 wave layout) ----
    float bv[4];
#pragma unroll
    for (int ni = 0; ni < 4; ++ni)
        bv[ni] = bias[(size_t)e * DOUT + n0 + ni * 16 + rl];
#pragma unroll
    for (int mi = 0; mi < 2; ++mi) {
#pragma unroll
        for (int j = 0; j < 4; ++j) {
            int rm = m0 + wave * 32 + mi * 16 + g * 4 + j;
            if (rm < cnt) {
                int s = sorted[start + rm];
                float* orow = out + (size_t)s * DOUT + n0 + rl;
#pragma unroll
                for (int ni = 0; ni < 4; ++ni)
                    orow[ni * 16] = acc[mi][ni][j] + bv[ni];
            }
        }
    }
}

extern "C" void kernel_launch(void* const* d_in, const int* in_sizes, int n_in,
                              void* d_out, int out_size, void* d_ws, size_t ws_size,
                              hipStream_t stream) {
    const float* xs      = (const float*)d_in[0];
    const float* mxs     = (const float*)d_in[1];
    const int*   actions = (const int*)d_in[2];
    const float* W       = (const float*)d_in[3];
    const float* b       = (const float*)d_in[4];
    float* out = (float*)d_out;

    int* ws_i   = (int*)d_ws;
    int* offs   = ws_i;          // [17]
    int* poffs  = ws_i + 20;     // [17]
    int* sorted = ws_i + 64;     // [BATCH] (ends at 4160)
    int* mte    = ws_i + 4224;   // [NMT_MAX]
    int* mtm0   = ws_i + 4224 + NMT_MAX;   // [NMT_MAX] (ends < 16384)

    sort_kernel<<<1, 1024, 0, stream>>>(actions, mxs,
                                        out + (size_t)BATCH * DOUT,
                                        offs, poffs, sorted, mte, mtm0);

    unsigned char* xws = (unsigned char*)d_ws + WS_X_OFF;
    xsplit_kernel<<<PADROWS / 16, 256, 0, stream>>>(xs, sorted, offs, poffs, xws);

    dim3 grid(NMT_MAX, DOUT / BN, 1);   // mt fastest: W-panel pairs adjacent
    gemm_kernel<<<grid, 256, 0, stream>>>(xws, W, b, offs, poffs, sorted,
                                          mte, mtm0, out);
}

// Round 19
// 163.387 us; speedup vs baseline: 1.2926x; 1.0901x over previous
//
#include <hip/hip_runtime.h>
#include <hip/hip_bf16.h>

#define BATCH 4096
#define NEXP  16
#define DIN   2048
#define DOUT  2048

#define BM 128
#define BN 64
#define NKT 64            // 64 k-tiles of 32 elements; processed as 32 pairs
#define NPAIR 32

#define WS_X_OFF   65536
#define PADROWS    4352   // 4096 + 16*16 worst-case padding
#define WS_X_BYTES ((size_t)PADROWS * 4096)

typedef __attribute__((ext_vector_type(4))) float f32x4;
typedef __attribute__((ext_vector_type(8))) short bf16x8;

// --- Kernel 1: bucket sample indices by expert; write mxs/actions tail ---
// poffs[e]: 16-aligned padded offsets (fragment groups never cross experts).
__global__ void sort_kernel(const int* __restrict__ actions,
                            const float* __restrict__ mxs,
                            float* __restrict__ out_tail,
                            int* __restrict__ offs,     // [17]
                            int* __restrict__ poffs,    // [17]
                            int* __restrict__ sorted) {
    __shared__ int s_cnt[NEXP];
    __shared__ int s_cur[NEXP];
    const int tid = threadIdx.x;
    if (tid < NEXP) s_cnt[tid] = 0;
    __syncthreads();
    for (int i = tid; i < BATCH; i += blockDim.x) {
        int a = actions[i];
        atomicAdd(&s_cnt[a], 1);
        out_tail[i] = mxs[i];
        out_tail[BATCH + i] = (float)a;
    }
    __syncthreads();
    if (tid == 0) {
        int run = 0, prun = 0;
        for (int e = 0; e < NEXP; ++e) {
            offs[e] = run;  s_cur[e] = run;
            poffs[e] = prun;
            run += s_cnt[e];
            prun += (s_cnt[e] + 15) & ~15;
        }
        offs[NEXP] = run;
        poffs[NEXP] = prun;
    }
    __syncthreads();
    // Bucket order is atomics-dependent, but each sample's output is computed
    // independently with fixed k-order -> output bit-deterministic.
    for (int i = tid; i < BATCH; i += blockDim.x) {
        int e = actions[i];
        int pos = atomicAdd(&s_cur[e], 1);
        sorted[pos] = i;
    }
}

// fp32 pair -> packed bf16 (round-to-nearest-even): [bf16(x1) | bf16(x0)]
__device__ __forceinline__ unsigned rne2(float x0, float x1) {
    unsigned b0 = __float_as_uint(x0), b1 = __float_as_uint(x1);
    b0 = b0 + 0x7FFFu + ((b0 >> 16) & 1u);
    b1 = b1 + 0x7FFFu + ((b1 >> 16) & 1u);
    return (b1 & 0xFFFF0000u) | (b0 >> 16);
}

// W LDS tile [64 rows][64 bf16] (one kt-PAIR): row = 128 B = 8 x 16B blocks,
// physical block = kb ^ (r&7) (r3/r7-class swizzle).
// Write (lanes 0-15 = rows 0-3, kb pairs {2q,2q^1}): banks 2-way -> free.
// Read (16-lane group, kb=j*4+g fixed, rows rl=0..15): slots s=kb^(r&7)
// distinct across r&7 -> 2-way -> free. (Measured ~0 conflicts r12/r15.)
__device__ __forceinline__ int lidxW(int r, int kb) {
    return r * 64 + ((kb ^ (r & 7)) << 3);
}

// --- Kernel 1b: X -> bf16 fragments, A-fragment-major ---
// Group = 16 padded rows of one expert = 64 KB: addr = grp*65536 + kt*1024
// + g*256 + slot*16. GEMM lane l reads grpbase + kt*1024 + l*16.
__global__ void xsplit_kernel(const float* __restrict__ xs,
                              const int* __restrict__ sorted,
                              const int* __restrict__ offs,
                              const int* __restrict__ poffs,
                              unsigned char* __restrict__ xws) {
    const int t = threadIdx.x;
    const int slot = t & 15;
    const int ktq = t >> 4;                 // 0..15, covers kt = ktq*4..+3
    const int p = blockIdx.x * 16 + slot;   // padded row index
    if (p >= poffs[NEXP]) return;
    int e = 0;
#pragma unroll
    for (int i = 1; i < NEXP; ++i)
        if (p >= poffs[i]) e = i;
    const int local = p - poffs[e];
    if (local >= offs[e + 1] - offs[e]) return;   // tail pad row
    const int src = sorted[offs[e] + local];
    const float* srow = xs + (size_t)src * DIN;
    unsigned char* gbase = xws + (size_t)blockIdx.x * 65536;
#pragma unroll
    for (int q = 0; q < 4; ++q) {
        const int kt = ktq * 4 + q;
        const float* s = srow + kt * 32;
        uint4 L[4];
#pragma unroll
        for (int j = 0; j < 4; ++j) {
            float4 a = *(const float4*)(s + 8 * j);
            float4 b = *(const float4*)(s + 8 * j + 4);
            L[j].x = rne2(a.x, a.y); L[j].y = rne2(a.z, a.w);
            L[j].z = rne2(b.x, b.y); L[j].w = rne2(b.z, b.w);
        }
        unsigned char* d = gbase + kt * 1024 + slot * 16;
#pragma unroll
        for (int g = 0; g < 4; ++g)
            *(uint4*)(d + g * 256) = L[g];
    }
}

// --- Kernel 2: grouped GEMM, pure bf16. kt-PAIR per KSTEP (16 MFMA/wave),
// 32 sync periods. X A-frags direct from xws (issued 1 period ahead);
// W fp32 regs 2-period pipeline -> conv -> dbuf LDS. Bare waitcnt asm with
// sched_barrier fences (no memory clobber). Waves 4x1. grid=(n,e,m).
// BEST MEASURED CONFIGURATION: 163.6-163.9 us total (r12/r15); every
// single-variable perturbation (BN 32, mt-grid, zero-sync, clobbers,
// BK 32, LDS X path) measured equal or worse (r9-r18).
__global__ __launch_bounds__(256, 3)
void gemm_kernel(const unsigned char* __restrict__ xws,
                 const float* __restrict__ W,
                 const float* __restrict__ bias,
                 const int* __restrict__ offs,
                 const int* __restrict__ poffs,
                 const int* __restrict__ sorted,
                 float* __restrict__ out) {
    __shared__ __align__(16) unsigned short Wl[2][BN * 64];  // 2 x 8 KB

    const int e = blockIdx.y;
    const int start = offs[e];
    const int cnt = offs[e + 1] - start;
    const int m0 = blockIdx.z * BM;
    if (m0 >= cnt) return;
    const int n0 = blockIdx.x * BN;

    const int tid = threadIdx.x;
    const int lane = tid & 63;
    const int wave = tid >> 6;
    const int g = lane >> 4, rl = lane & 15;

    // W staging: row swr (0..63), 16-fp32 chunk wkq (0..3) per pair.
    const int swr = tid >> 2;
    const int wkq = tid & 3;
    const float* wsrc = W + ((size_t)e * DOUT + n0 + swr) * DIN + wkq * 16;

    // X fragment group bases; clamp to buffer (OOB-safe: clamped groups only
    // contain rows >= cnt, never written back).
    const unsigned char* xb[2];
#pragma unroll
    for (int mi = 0; mi < 2; ++mi) {
        int prow = poffs[e] + m0 + wave * 32 + mi * 16;
        if (prow > PADROWS - 16) prow = PADROWS - 16;
        xb[mi] = xws + ((size_t)prow >> 4) * 65536 + (size_t)lane * 16;
    }

    f32x4 acc[2][4];
#pragma unroll
    for (int i = 0; i < 2; ++i)
#pragma unroll
        for (int j = 0; j < 4; ++j) acc[i][j] = (f32x4){0.f, 0.f, 0.f, 0.f};

    // ---- prologue ----
    float4 pwA[4], pwB[4];
#pragma unroll
    for (int j = 0; j < 4; ++j) pwA[j] = *(const float4*)(wsrc + 0 * 64 + 4 * j);  // pair 0
#pragma unroll
    for (int j = 0; j < 4; ++j) pwB[j] = *(const float4*)(wsrc + 1 * 64 + 4 * j);  // pair 1
    bf16x8 axA[2][2], axB[2][2];
#pragma unroll
    for (int mi = 0; mi < 2; ++mi) {
        axA[mi][0] = *(const bf16x8*)(xb[mi]);            // kt 0
        axA[mi][1] = *(const bf16x8*)(xb[mi] + 1024);     // kt 1
    }
    {   // pre-loop: conv + ds_write pair 0 into buf 0; reload pwA with pair 2
        uint4 u0, u1;
        u0.x = rne2(pwA[0].x, pwA[0].y); u0.y = rne2(pwA[0].z, pwA[0].w);
        u0.z = rne2(pwA[1].x, pwA[1].y); u0.w = rne2(pwA[1].z, pwA[1].w);
        u1.x = rne2(pwA[2].x, pwA[2].y); u1.y = rne2(pwA[2].z, pwA[2].w);
        u1.z = rne2(pwA[3].x, pwA[3].y); u1.w = rne2(pwA[3].z, pwA[3].w);
        *(uint4*)&Wl[0][lidxW(swr, 2 * wkq)]     = u0;
        *(uint4*)&Wl[0][lidxW(swr, 2 * wkq + 1)] = u1;
#pragma unroll
        for (int j = 0; j < 4; ++j) pwA[j] = *(const float4*)(wsrc + 2 * 64 + 4 * j);
    }

    int pr = 0;   // pair index

    // Per KSTEP(pair pr): [lgkm0 + barrier] -> read W frags (buf pr&1) ->
    // issue X(pair pr+1) -> conv+write W(pair pr+1) into other buf ->
    // reload PWU with W(pair pr+3) -> 16 MFMA.
    // Race audit: reads of buf B in KSTEP p are drained (own lgkmcnt(0))
    // before the barrier of KSTEP p+1, which precedes writes to buf B.
#define KSTEP(AXC, AXN, PWU, PAR) do {                                         \
    __builtin_amdgcn_sched_barrier(0);                                         \
    asm volatile("s_waitcnt lgkmcnt(0)");                                      \
    __builtin_amdgcn_sched_barrier(0);                                         \
    __builtin_amdgcn_s_barrier();                                              \
    __builtin_amdgcn_sched_barrier(0);                                         \
    bf16x8 bh[2][4];                                                           \
    _Pragma("unroll")                                                          \
    for (int j = 0; j < 2; ++j)                                                \
        _Pragma("unroll")                                                      \
        for (int ni = 0; ni < 4; ++ni)                                         \
            bh[j][ni] = *(const bf16x8*)&Wl[PAR][lidxW(ni * 16 + rl, j * 4 + g)]; \
    { /* X(pair pr+1) loads -> AXN (wrap: harmless reload) */                  \
      int _kn = ((pr + 1) & (NPAIR - 1)) * 2;                                  \
      _Pragma("unroll")                                                        \
      for (int mi = 0; mi < 2; ++mi) {                                         \
          AXN[mi][0] = *(const bf16x8*)(xb[mi] + (size_t)_kn * 1024);          \
          AXN[mi][1] = *(const bf16x8*)(xb[mi] + (size_t)(_kn + 1) * 1024);    \
      } }                                                                      \
    { /* conv + ds_write W(pair pr+1) into other buffer */                     \
      uint4 u0, u1;                                                            \
      u0.x = rne2(PWU[0].x, PWU[0].y); u0.y = rne2(PWU[0].z, PWU[0].w);        \
      u0.z = rne2(PWU[1].x, PWU[1].y); u0.w = rne2(PWU[1].z, PWU[1].w);        \
      u1.x = rne2(PWU[2].x, PWU[2].y); u1.y = rne2(PWU[2].z, PWU[2].w);        \
      u1.z = rne2(PWU[3].x, PWU[3].y); u1.w = rne2(PWU[3].z, PWU[3].w);        \
      *(uint4*)&Wl[PAR ^ 1][lidxW(swr, 2 * wkq)]     = u0;                     \
      *(uint4*)&Wl[PAR ^ 1][lidxW(swr, 2 * wkq + 1)] = u1; }                   \
    { /* reload PWU with W(pair pr+3) */                                       \
      int _k3 = (pr + 3) & (NPAIR - 1);                                        \
      _Pragma("unroll")                                                        \
      for (int j = 0; j < 4; ++j)                                              \
          PWU[j] = *(const float4*)(wsrc + (size_t)_k3 * 64 + 4 * j); }        \
    __builtin_amdgcn_s_setprio(1);                                             \
    _Pragma("unroll")                                                          \
    for (int j = 0; j < 2; ++j)                                                \
        _Pragma("unroll")                                                      \
        for (int mi = 0; mi < 2; ++mi)                                         \
            _Pragma("unroll")                                                  \
            for (int ni = 0; ni < 4; ++ni)                                     \
                acc[mi][ni] = __builtin_amdgcn_mfma_f32_16x16x32_bf16(AXC[mi][j], bh[j][ni], acc[mi][ni], 0, 0, 0); \
    __builtin_amdgcn_s_setprio(0);                                             \
    ++pr;                                                                      \
} while (0)

#pragma unroll 1
    for (int it = 0; it < NPAIR / 2; ++it) {
        KSTEP(axA, axB, pwB, 0);   // even pair: X in axA, W buf 0
        KSTEP(axB, axA, pwA, 1);   // odd  pair
    }
#undef KSTEP

    // ---- epilogue: bias add + scatter rows (4x1 wave layout) ----
    float bv[4];
#pragma unroll
    for (int ni = 0; ni < 4; ++ni)
        bv[ni] = bias[(size_t)e * DOUT + n0 + ni * 16 + rl];
#pragma unroll
    for (int mi = 0; mi < 2; ++mi) {
#pragma unroll
        for (int j = 0; j < 4; ++j) {
            int rm = m0 + wave * 32 + mi * 16 + g * 4 + j;
            if (rm < cnt) {
                int s = sorted[start + rm];
                float* orow = out + (size_t)s * DOUT + n0 + rl;
#pragma unroll
                for (int ni = 0; ni < 4; ++ni)
                    orow[ni * 16] = acc[mi][ni][j] + bv[ni];
            }
        }
    }
}

// --- Fallback (round-5 proven 3-product kernel) if workspace too small ---
__device__ __forceinline__ void split_pair(float x0, float x1, unsigned& h, unsigned& l) {
    unsigned b0 = __float_as_uint(x0), b1 = __float_as_uint(x1);
    unsigned h0 = b0 & 0xFFFF0000u;
    unsigned h1 = b1 & 0xFFFF0000u;
    h = h1 | (b0 >> 16);
    unsigned l0 = __float_as_uint(x0 - __uint_as_float(h0));
    unsigned l1 = __float_as_uint(x1 - __uint_as_float(h1));
    l = (l1 & 0xFFFF0000u) | (l0 >> 16);
}
__device__ __forceinline__ void split_f4pair(float4 a, float4 b, uint4& h, uint4& l) {
    split_pair(a.x, a.y, h.x, l.x);
    split_pair(a.z, a.w, h.y, l.y);
    split_pair(b.x, b.y, h.z, l.z);
    split_pair(b.z, b.w, h.w, l.w);
}
__device__ __forceinline__ int lidx(int r, int kb) {
    return r * 64 + ((kb ^ (r & 7)) << 3);
}

__global__ __launch_bounds__(256, 3)
void gemm_fb(const float* __restrict__ xs,
             const float* __restrict__ W,
             const float* __restrict__ bias,
             const int* __restrict__ offs,
             const int* __restrict__ sorted,
             float* __restrict__ out) {
    __shared__ __align__(16) unsigned short Xs[128 * 64];
    __shared__ __align__(16) unsigned short Ws[64 * 64];

    const int e = blockIdx.y;
    const int start = offs[e];
    const int cnt = offs[e + 1] - start;
    const int m0 = blockIdx.z * 128;
    if (m0 >= cnt) return;
    const int n0 = blockIdx.x * 64;

    const int tid = threadIdx.x;
    const int lane = tid & 63;
    const int wave = tid >> 6;
    const int wm = wave >> 1, wn = wave & 1;
    const int srow = tid & 127, kq = tid >> 7;
    const int swr = tid >> 2, wkq = tid & 3;

    const int rm_s = m0 + srow;
    const int xrow = (rm_s < cnt) ? sorted[start + rm_s] : -1;
    const float* xsrc = xs + (size_t)(xrow < 0 ? 0 : xrow) * DIN + kq * 16;
    const float* wsrc = W + ((size_t)e * DOUT + n0 + swr) * DIN + wkq * 8;

    f32x4 acc[4][2];
#pragma unroll
    for (int i = 0; i < 4; ++i)
#pragma unroll
        for (int j = 0; j < 2; ++j) acc[i][j] = (f32x4){0.f, 0.f, 0.f, 0.f};

    float4 px[4], pw[2];
#pragma unroll
    for (int j = 0; j < 4; ++j)
        px[j] = (xrow >= 0) ? *(const float4*)(xsrc + j * 4) : make_float4(0.f, 0.f, 0.f, 0.f);
    pw[0] = *(const float4*)(wsrc);
    pw[1] = *(const float4*)(wsrc + 4);

    for (int k0 = 0; k0 < DIN; k0 += 32) {
        {
            uint4 xh0, xl0, xh1, xl1, wh, wl;
            split_f4pair(px[0], px[1], xh0, xl0);
            split_f4pair(px[2], px[3], xh1, xl1);
            split_f4pair(pw[0], pw[1], wh, wl);
            *(uint4*)&Xs[lidx(srow, 2 * kq)]         = xh0;
            *(uint4*)&Xs[lidx(srow, 2 * kq + 1)]     = xh1;
            *(uint4*)&Xs[lidx(srow, 4 + 2 * kq)]     = xl0;
            *(uint4*)&Xs[lidx(srow, 4 + 2 * kq + 1)] = xl1;
            *(uint4*)&Ws[lidx(swr, wkq)]             = wh;
            *(uint4*)&Ws[lidx(swr, 4 + wkq)]         = wl;
        }
        __syncthreads();
        {
            int kn = (k0 + 32 < DIN) ? (k0 + 32) : 0;
#pragma unroll
            for (int j = 0; j < 4; ++j)
                px[j] = (xrow >= 0) ? *(const float4*)(xsrc + kn + j * 4) : make_float4(0.f, 0.f, 0.f, 0.f);
            pw[0] = *(const float4*)(wsrc + kn);
            pw[1] = *(const float4*)(wsrc + kn + 4);
        }
        {
            const int gg = lane >> 4, rrl = lane & 15;
            bf16x8 ah[4], al[4], bh[2], bl[2];
#pragma unroll
            for (int mi = 0; mi < 4; ++mi) {
                int R = wm * 64 + mi * 16 + rrl;
                ah[mi] = *(const bf16x8*)&Xs[lidx(R, gg)];
                al[mi] = *(const bf16x8*)&Xs[lidx(R, 4 + gg)];
            }
#pragma unroll
            for (int ni = 0; ni < 2; ++ni) {
                int R = wn * 32 + ni * 16 + rrl;
                bh[ni] = *(const bf16x8*)&Ws[lidx(R, gg)];
                bl[ni] = *(const bf16x8*)&Ws[lidx(R, 4 + gg)];
            }
#pragma unroll
            for (int mi = 0; mi < 4; ++mi)
#pragma unroll
                for (int ni = 0; ni < 2; ++ni)
                    acc[mi][ni] = __builtin_amdgcn_mfma_f32_16x16x32_bf16(ah[mi], bh[ni], acc[mi][ni], 0, 0, 0);
#pragma unroll
            for (int mi = 0; mi < 4; ++mi)
#pragma unroll
                for (int ni = 0; ni < 2; ++ni)
                    acc[mi][ni] = __builtin_amdgcn_mfma_f32_16x16x32_bf16(ah[mi], bl[ni], acc[mi][ni], 0, 0, 0);
#pragma unroll
            for (int mi = 0; mi < 4; ++mi)
#pragma unroll
                for (int ni = 0; ni < 2; ++ni)
                    acc[mi][ni] = __builtin_amdgcn_mfma_f32_16x16x32_bf16(al[mi], bh[ni], acc[mi][ni], 0, 0, 0);
        }
        __syncthreads();
    }

    const int gg = lane >> 4, rrl = lane & 15;
    float bv[2];
#pragma unroll
    for (int ni = 0; ni < 2; ++ni)
        bv[ni] = bias[(size_t)e * DOUT + n0 + wn * 32 + ni * 16 + rrl];
#pragma unroll
    for (int mi = 0; mi < 4; ++mi) {
#pragma unroll
        for (int j = 0; j < 4; ++j) {
            int rm = m0 + wm * 64 + mi * 16 + gg * 4 + j;
            if (rm < cnt) {
                int s = sorted[start + rm];
                float* orow = out + (size_t)s * DOUT + n0 + wn * 32 + rrl;
#pragma unroll
                for (int ni = 0; ni < 2; ++ni)
                    orow[ni * 16] = acc[mi][ni][j] + bv[ni];
            }
        }
    }
}

extern "C" void kernel_launch(void* const* d_in, const int* in_sizes, int n_in,
                              void* d_out, int out_size, void* d_ws, size_t ws_size,
                              hipStream_t stream) {
    const float* xs      = (const float*)d_in[0];
    const float* mxs     = (const float*)d_in[1];
    const int*   actions = (const int*)d_in[2];
    const float* W       = (const float*)d_in[3];
    const float* b       = (const float*)d_in[4];
    float* out = (float*)d_out;

    int* ws_i   = (int*)d_ws;
    int* offs   = ws_i;          // [17]
    int* poffs  = ws_i + 20;     // [17]
    int* sorted = ws_i + 64;     // [BATCH]

    sort_kernel<<<1, 1024, 0, stream>>>(actions, mxs,
                                        out + (size_t)BATCH * DOUT,
                                        offs, poffs, sorted);

    if (ws_size >= WS_X_OFF + WS_X_BYTES) {
        unsigned char* xws = (unsigned char*)d_ws + WS_X_OFF;
        xsplit_kernel<<<PADROWS / 16, 256, 0, stream>>>(xs, sorted, offs, poffs, xws);
        dim3 grid(DOUT / BN, NEXP, BATCH / BM);   // n fastest: dense active prefix
        gemm_kernel<<<grid, 256, 0, stream>>>(xws, W, b, offs, poffs, sorted, out);
    } else {
        dim3 grid(DOUT / 64, NEXP, BATCH / 128);
        gemm_fb<<<grid, 256, 0, stream>>>(xs, W, b, offs, sorted, out);
    }
}